// Round 17
// baseline (706.169 us; speedup 1.0000x reference)
//
#include <hip/hip_runtime.h>
#include <math.h>

#define N_NODES 100000
#define N_EDGES 1600000
#define CSTRIDE 48   // fixed CSR stride (ints): max degree for E/N=16 Poisson ~36, P(>48)~1e-9/node
#define NGRP 8       // XCD groups for the CSR build
#define NODES_PER_GRP ((N_NODES + NGRP - 1) / NGRP)   // 12500
#define GRU_NT (N_NODES / 32)                          // 3125 tiles

typedef __attribute__((ext_vector_type(8))) short short8;
typedef __attribute__((ext_vector_type(4))) float f32x4;

__device__ inline unsigned short f32_to_bf16(float x) {
    unsigned u = __float_as_uint(x);
    unsigned r = u + 0x7fff + ((u >> 16) & 1);   // RNE
    return (unsigned short)(r >> 16);
}
__device__ inline float bf16_to_f32(unsigned short u) {
    return __uint_as_float(((unsigned)u) << 16);
}
__device__ inline void split1(float x, unsigned short& hi, unsigned short& lo) {
    hi = f32_to_bf16(x);
    lo = f32_to_bf16(x - bf16_to_f32(hi));
}
// 1-transcendental tanh: exact limits at +/-inf, ~1e-6 abs err.
__device__ inline float fast_tanh(float x) {
    float ax = fabsf(x);
    float e  = __expf(2.f * ax);
    float t  = 1.f - 2.f / (e + 1.f);
    return copysignf(t, x);
}

// Packed-fragment index for a [384][128] bf16 matrix (B-operand layout):
// element (g,k): w=(g&127)>>4, gate=g>>7, l15=g&15, k0=k>>5, hi8=(k&31)>>3,
// j=k&7, lane=hi8*16+l15 ; short idx = (((w*3+gate)*4+k0)*64+lane)*8+j.
// One wave fragment = one contiguous 1KB burst; col-half ch occupies the
// contiguous slice [ch*24576, (ch+1)*24576) shorts.
__device__ inline size_t pack_idx(int g, int k) {
    int gate = g >> 7, c = g & 127;
    int w = c >> 4, l15 = c & 15;
    int k0 = k >> 5, r = k & 31, hi8 = r >> 3, j = r & 7;
    int lane = hi8 * 16 + l15;
    return ((size_t)(((w * 3 + gate) * 4 + k0) * 64 + lane)) * 8 + j;
}

// ---------------------------------------------------------------- W_c, bc ---
__global__ __launch_bounds__(128) void pack_wc_kernel(const float* __restrict__ W_ih,
                                                      const float* __restrict__ W,
                                                      unsigned short* __restrict__ Wcpk) {
    int g = blockIdx.x;          // 0..383
    int k = threadIdx.x;         // 0..127
    float acc = 0.f;
    for (int j = 0; j < 128; ++j)
        acc += W_ih[g * 128 + j] * W[j * 128 + k];
    Wcpk[pack_idx(g, k)] = f32_to_bf16(acc);
}

__global__ __launch_bounds__(256) void pack_whh_kernel(const float* __restrict__ W_hh,
                                                       unsigned short* __restrict__ Whpk) {
    int i = blockIdx.x * 256 + threadIdx.x;
    if (i >= 384 * 128) return;
    Whpk[pack_idx(i >> 7, i & 127)] = f32_to_bf16(W_hh[i]);
}

__global__ __launch_bounds__(384) void bc_kernel(const float* __restrict__ W_ih,
                                                 const float* __restrict__ b,
                                                 float* __restrict__ bc) {
    int g = threadIdx.x;
    if (g >= 384) return;
    float acc = 0.f;
    for (int j = 0; j < 128; ++j)
        acc += W_ih[g * 128 + j] * b[j];
    bc[g] = acc;
}

// ---------------------------------------------------------------- init h ----
__global__ __launch_bounds__(256) void init_h_kernel(const float* __restrict__ f,
                                                     unsigned short* __restrict__ h_hi,
                                                     unsigned short* __restrict__ h_lo) {
    int idx = blockIdx.x * 256 + threadIdx.x;          // over N*32 float4
    if (idx >= N_NODES * 32) return;
    int r = idx >> 5, c4 = idx & 31;
    float4 v = make_float4(0.f, 0.f, 0.f, 0.f);
    if (c4 < 16) v = ((const float4*)f)[r * 16 + c4];
    ushort4 hv, lv;
    split1(v.x, hv.x, lv.x); split1(v.y, hv.y, lv.y);
    split1(v.z, hv.z, lv.z); split1(v.w, hv.w, lv.w);
    ((ushort4*)h_hi)[idx] = hv;
    ((ushort4*)h_lo)[idx] = lv;
}

// ---------------------------------------------------------------- finalize --
__global__ __launch_bounds__(256) void finalize_kernel(const unsigned short* __restrict__ h_hi,
                                                       const unsigned short* __restrict__ h_lo,
                                                       float* __restrict__ out) {
    int idx = blockIdx.x * 256 + threadIdx.x;          // over N*32 quads
    if (idx >= N_NODES * 32) return;
    ushort4 hv = ((const ushort4*)h_hi)[idx];
    ushort4 lv = ((const ushort4*)h_lo)[idx];
    float4 o;
    o.x = bf16_to_f32(hv.x) + bf16_to_f32(lv.x);
    o.y = bf16_to_f32(hv.y) + bf16_to_f32(lv.y);
    o.z = bf16_to_f32(hv.z) + bf16_to_f32(lv.z);
    o.w = bf16_to_f32(hv.w) + bf16_to_f32(lv.w);
    ((float4*)out)[idx] = o;
}

// ---------------------------------------------------------------- CSR build -
__global__ __launch_bounds__(256) void fill_xcd_kernel(const int* __restrict__ src,
                                                       const int* __restrict__ dst,
                                                       int* __restrict__ cnt,
                                                       int* __restrict__ csr_src) {
    const int grp  = blockIdx.x & (NGRP - 1);
    const int bing = blockIdx.x / NGRP;          // block index within group
    const int nbg  = gridDim.x / NGRP;           // blocks per group
    const int lo   = grp * NODES_PER_GRP;
    const int hi   = lo + NODES_PER_GRP;
    for (int e = bing * 256 + threadIdx.x; e < N_EDGES; e += nbg * 256) {
        int d = __builtin_nontemporal_load(dst + e);
        if (d >= lo && d < hi) {
            int s = __builtin_nontemporal_load(src + e);
            int pos = atomicAdd(&cnt[d], 1);
            if (pos < CSTRIDE) csr_src[(size_t)d * CSTRIDE + pos] = s;
        }
    }
}

// ---------------------------------------------------------------- gather ----
// s_pair[n] = split( sum_{in-edges} h_hi[src] )   one wave per node.
// ALL index loads then ALL row loads are issued up-front into compile-time
// indexed register arrays (deg is wave-uniform -> guards are uniform, no
// divergence): exactly TWO latency exposures per node instead of 2-6
// dependent batches. deg<=48 by CSTRIDE.
__global__ __launch_bounds__(256, 2) void gather_kernel(const unsigned int* __restrict__ hhu,
                                                        const int* __restrict__ cnt,
                                                        const int* __restrict__ csr_src,
                                                        unsigned short* __restrict__ s_hi,
                                                        unsigned short* __restrict__ s_lo) {
    int node = blockIdx.x * 4 + (threadIdx.x >> 6);
    int lane = threadIdx.x & 63;
    int deg = cnt[node];
    int end = (deg < CSTRIDE) ? deg : CSTRIDE;
    const int* lst = csr_src + (size_t)node * CSTRIDE;
    const int nb = end & ~7;

    int li[48];
#pragma unroll
    for (int base = 0; base < 48; base += 8) {
        if (base < nb) {
            int4 p0 = *(const int4*)&lst[base];
            int4 p1 = *(const int4*)&lst[base + 4];
            li[base + 0] = p0.x; li[base + 1] = p0.y; li[base + 2] = p0.z; li[base + 3] = p0.w;
            li[base + 4] = p1.x; li[base + 5] = p1.y; li[base + 6] = p1.z; li[base + 7] = p1.w;
        }
    }
    unsigned u[48];
#pragma unroll
    for (int base = 0; base < 48; base += 8) {
        if (base < nb) {
#pragma unroll
            for (int j = 0; j < 8; ++j)
                u[base + j] = hhu[(size_t)li[base + j] * 64 + lane];
        }
    }
    float a0 = 0.f, a1 = 0.f;
#pragma unroll
    for (int base = 0; base < 48; base += 8) {
        if (base < nb) {
#pragma unroll
            for (int j = 0; j < 8; ++j) {
                a0 += __uint_as_float(u[base + j] << 16);
                a1 += __uint_as_float(u[base + j] & 0xffff0000u);
            }
        }
    }
    for (int i = nb; i < end; ++i) {
        unsigned u0 = hhu[(size_t)lst[i] * 64 + lane];
        a0 += __uint_as_float(u0 << 16);
        a1 += __uint_as_float(u0 & 0xffff0000u);
    }
    unsigned short h0, l0, h1, l1;
    split1(a0, h0, l0);
    split1(a1, h1, l1);
    ((ushort2*)s_hi)[(size_t)node * 64 + lane] = (ushort2){h0, h1};
    ((ushort2*)s_lo)[(size_t)node * 64 + lane] = (ushort2){l0, l1};
}

// ---------------------------------------------------------------- GRU -------
// LDS-weight-stationary GRU + async reg-staged act pipeline (T14) with
// double-buffered, XOR-swizzled act LDS. h ping-pong -> h_in read-only, so
// the ONLY barrier is the per-tile LDS buffer flip (proved safe: a wave can
// be at most 1 iteration ahead across a single barrier, and it writes the
// OTHER buffer).
// Per tile: ds_write staged regs -> barrier -> issue next tile's global
// loads (latency hides under MFMA) -> hold/deg loads -> MFMA from LDS ->
// gates -> stores. Acts swizzled byte^=((row&7)<<4): <=2-way banks on both
// write and b128 read. Weight frags hoisted LDS->regs once (if regalloc
// demotes them it falls back to ds_read — no global-latency downside).
__global__ __launch_bounds__(512, 1) void gru_ps2_kernel(
        const unsigned short* __restrict__ s_hi,
        const unsigned short* __restrict__ s_lo,
        const unsigned short* __restrict__ hin_hi,
        const unsigned short* __restrict__ hin_lo,
        unsigned short* __restrict__ hout_hi,
        unsigned short* __restrict__ hout_lo,
        const unsigned short* __restrict__ Wcpk,
        const unsigned short* __restrict__ Whpk,
        const float* __restrict__ bc,
        const float* __restrict__ b_ih,
        const float* __restrict__ b_hh,
        const int* __restrict__ cnt) {
    __shared__ unsigned short lwc[24576];        // 48KB Wc col-half
    __shared__ unsigned short lwh[24576];        // 48KB Whh col-half
    __shared__ unsigned short abuf[2][3][4096];  // 2 x {s_hi,s_lo,h_hi} x 8KB

    const int tid  = threadIdx.x;
    const int lane = tid & 63;
    const int wv   = tid >> 6;              // 0..7
    const int w4   = wv & 3;                // col slice within half
    const int nt   = wv >> 2;               // node subtile 0/1
    const int l15  = lane & 15, hi8 = lane >> 4;
    const int ch   = blockIdx.x & 1;
    const int c    = ch * 64 + w4 * 16 + l15;

    // ---- stage this col-half's weights into LDS (once per block)
    {
        const ushort4* gC = (const ushort4*)(Wcpk + (size_t)ch * 24576);
        const ushort4* gH = (const ushort4*)(Whpk + (size_t)ch * 24576);
        ushort4* dC = (ushort4*)lwc;
        ushort4* dH = (ushort4*)lwh;
#pragma unroll
        for (int i = 0; i < 12; ++i) {
            dC[tid + 512 * i] = gC[tid + 512 * i];
            dH[tid + 512 * i] = gH[tid + 512 * i];
        }
    }
    __syncthreads();

    // ---- hoist weight fragments to registers (24 x b128, once)
    short8 wcr[3][4], whr[3][4];
#pragma unroll
    for (int g = 0; g < 3; ++g)
#pragma unroll
        for (int k0 = 0; k0 < 4; ++k0) {
            int fo = (((w4 * 3 + g) * 4 + k0) * 64 + lane) * 8;
            wcr[g][k0] = *(const short8*)&lwc[fo];
            whr[g][k0] = *(const short8*)&lwh[fo];
        }

    const float bcr = bc[c],   bcz = bc[128 + c],   bcn = bc[256 + c];
    const float bir = b_ih[c], biz = b_ih[128 + c], bin = b_ih[256 + c];
    const float bhr = b_hh[c], bhz = b_hh[128 + c], bhn = b_hh[256 + c];

    // ---- act staging geometry: thread owns 16B chunk o of the 8KB tile
    const int o  = tid * 16;                         // linear byte offset
    const int os = o ^ (((o >> 8) & 7) << 4);        // swizzled LDS offset
    // A-fragment read offsets (swizzled)
    const int arow = nt * 16 + l15;
    const int asw  = (arow & 7) << 4;

    const int tstep = gridDim.x >> 1;                // 256
    int tile = blockIdx.x >> 1;

    short8 rs, rl, rh;
    if (tile < GRU_NT) {
        size_t gb = (size_t)tile * 32 * 256 + o;     // byte offset into acts
        rs = *(const short8*)((const char*)s_hi  + gb);
        rl = *(const short8*)((const char*)s_lo  + gb);
        rh = *(const short8*)((const char*)hin_hi + gb);
    }
    int pb = 0;
    for (; tile < GRU_NT; tile += tstep) {
        // ---- commit staged regs to LDS buf pb, flip barrier
        *(short8*)((char*)abuf[pb][0] + os) = rs;
        *(short8*)((char*)abuf[pb][1] + os) = rl;
        *(short8*)((char*)abuf[pb][2] + os) = rh;
        __syncthreads();

        // ---- issue next tile's global loads (hide under MFMA below)
        int ntile = tile + tstep;
        if (ntile < GRU_NT) {
            size_t gb = (size_t)ntile * 32 * 256 + o;
            rs = *(const short8*)((const char*)s_hi  + gb);
            rl = *(const short8*)((const char*)s_lo  + gb);
            rh = *(const short8*)((const char*)hin_hi + gb);
        }

        // ---- hold + deg (own coords; issued before MFMA to overlap)
        const int n0 = tile * 32 + nt * 16;
        float hold[4], dg[4];
#pragma unroll
        for (int r = 0; r < 4; ++r) {
            int row = n0 + hi8 * 4 + r;
            size_t gidx = (size_t)row * 128 + c;
            hold[r] = bf16_to_f32(hin_hi[gidx]) + bf16_to_f32(hin_lo[gidx]);
            dg[r]   = (float)cnt[row];
        }

        // ---- MFMAs from act LDS + register weights
        f32x4 z1[3], z2[3];
#pragma unroll
        for (int g = 0; g < 3; ++g) {
            z1[g] = (f32x4){0.f, 0.f, 0.f, 0.f};
            z2[g] = (f32x4){0.f, 0.f, 0.f, 0.f};
        }
#pragma unroll
        for (int k0 = 0; k0 < 4; ++k0) {
            int pa = arow * 256 + k0 * 64 + hi8 * 16;   // logical byte offset
            int ps = pa ^ asw;
            short8 ash = *(const short8*)((const char*)abuf[pb][0] + ps);
            short8 asl = *(const short8*)((const char*)abuf[pb][1] + ps);
            short8 ahh = *(const short8*)((const char*)abuf[pb][2] + ps);
#pragma unroll
            for (int g = 0; g < 3; ++g) {
                z1[g] = __builtin_amdgcn_mfma_f32_16x16x32_bf16(ash, wcr[g][k0], z1[g], 0, 0, 0);
                z1[g] = __builtin_amdgcn_mfma_f32_16x16x32_bf16(asl, wcr[g][k0], z1[g], 0, 0, 0);
                z2[g] = __builtin_amdgcn_mfma_f32_16x16x32_bf16(ahh, whr[g][k0], z2[g], 0, 0, 0);
            }
        }

        // ---- gates + h_out pair (disjoint from h_in: no extra barrier)
#pragma unroll
        for (int r = 0; r < 4; ++r) {
            int row = n0 + hi8 * 4 + r;
            size_t gidx = (size_t)row * 128 + c;
            float d = dg[r];
            float rr = 1.f / (1.f + __expf(-(z1[0][r] + d * bcr + bir + z2[0][r] + bhr)));
            float zz = 1.f / (1.f + __expf(-(z1[1][r] + d * bcz + biz + z2[1][r] + bhz)));
            float nn_ = fast_tanh(z1[2][r] + d * bcn + bin + rr * (z2[2][r] + bhn));
            float hn = (1.f - zz) * nn_ + zz * hold[r];
            unsigned short shh, sll;
            split1(hn, shh, sll);
            hout_hi[gidx] = shh;
            hout_lo[gidx] = sll;
        }
        pb ^= 1;
    }
}

// ---------------------------------------------------------------- launch ----
extern "C" void kernel_launch(void* const* d_in, const int* in_sizes, int n_in,
                              void* d_out, int out_size, void* d_ws, size_t ws_size,
                              hipStream_t stream) {
    const float* feat = (const float*)d_in[0];
    const float* W    = (const float*)d_in[1];
    const float* b    = (const float*)d_in[2];
    const float* W_ih = (const float*)d_in[3];
    const float* W_hh = (const float*)d_in[4];
    const float* b_ih = (const float*)d_in[5];
    const float* b_hh = (const float*)d_in[6];
    const int*   src  = (const int*)d_in[7];
    const int*   dst  = (const int*)d_in[8];

    // s-pair parks in d_out during the steps (exact fit: N*128*4 bytes);
    // finalize_kernel rewrites d_out with f32 h at the end.
    unsigned short* s_hi = (unsigned short*)d_out;
    unsigned short* s_lo = s_hi + (size_t)N_NODES * 128;

    char* w = (char*)d_ws;
    unsigned short* hA_hi = (unsigned short*)w; w += (size_t)N_NODES * 128 * 2;
    unsigned short* hA_lo = (unsigned short*)w; w += (size_t)N_NODES * 128 * 2;
    unsigned short* hB_hi = (unsigned short*)w; w += (size_t)N_NODES * 128 * 2;
    unsigned short* hB_lo = (unsigned short*)w; w += (size_t)N_NODES * 128 * 2;
    unsigned short* Wcpk  = (unsigned short*)w; w += (size_t)384 * 128 * 2;
    unsigned short* Whpk  = (unsigned short*)w; w += (size_t)384 * 128 * 2;
    float*          bc    = (float*)w;          w += 384 * 4;
    int*            cnt   = (int*)w;            w += (size_t)N_NODES * 4;
    int*            csr_src = (int*)w;          w += (size_t)N_NODES * CSTRIDE * 4;  // 19.2 MB

    const int elem_blocks = (N_NODES * 32 + 255) / 256;
    const int gath_blocks = N_NODES / 4;                  // 25000 (exact)

    init_h_kernel<<<elem_blocks, 256, 0, stream>>>(feat, hA_hi, hA_lo);
    pack_wc_kernel<<<384, 128, 0, stream>>>(W_ih, W, Wcpk);
    pack_whh_kernel<<<(384 * 128 + 255) / 256, 256, 0, stream>>>(W_hh, Whpk);
    bc_kernel<<<1, 384, 0, stream>>>(W_ih, b, bc);

    // ---- XCD-partitioned bucket CSR (one pass; cnt = exact degrees)
    hipMemsetAsync(cnt, 0, (size_t)N_NODES * 4, stream);
    fill_xcd_kernel<<<1024, 256, 0, stream>>>(src, dst, cnt, csr_src);

    // ---- 3 steps with h ping-pong: A->B, B->A, A->B
    unsigned short* hi_in[3]  = {hA_hi, hB_hi, hA_hi};
    unsigned short* lo_in[3]  = {hA_lo, hB_lo, hA_lo};
    unsigned short* hi_out[3] = {hB_hi, hA_hi, hB_hi};
    unsigned short* lo_out[3] = {hB_lo, hA_lo, hB_lo};
    for (int s = 0; s < 3; ++s) {
        gather_kernel<<<gath_blocks, 256, 0, stream>>>((const unsigned int*)hi_in[s],
                                                       cnt, csr_src, s_hi, s_lo);
        gru_ps2_kernel<<<512, 512, 0, stream>>>(s_hi, s_lo,
                                                hi_in[s], lo_in[s],
                                                hi_out[s], lo_out[s],
                                                Wcpk, Whpk, bc, b_ih, b_hh, cnt);
    }
    finalize_kernel<<<elem_blocks, 256, 0, stream>>>(hB_hi, hB_lo, (float*)d_out);
}

// Round 18
// 546.512 us; speedup vs baseline: 1.2921x; 1.2921x over previous
//
#include <hip/hip_runtime.h>
#include <math.h>

#define N_NODES 100000
#define N_EDGES 1600000
#define CSTRIDE 48   // fixed CSR stride (ints): max degree for E/N=16 Poisson ~36, P(>48)~1e-9/node
#define NGRP 8       // XCD groups for the CSR build
#define NODES_PER_GRP ((N_NODES + NGRP - 1) / NGRP)   // 12500
#define GRU_NT (N_NODES / 32)                          // 3125 tiles

typedef __attribute__((ext_vector_type(8))) short short8;
typedef __attribute__((ext_vector_type(4))) float f32x4;

__device__ inline unsigned short f32_to_bf16(float x) {
    unsigned u = __float_as_uint(x);
    unsigned r = u + 0x7fff + ((u >> 16) & 1);   // RNE
    return (unsigned short)(r >> 16);
}
__device__ inline float bf16_to_f32(unsigned short u) {
    return __uint_as_float(((unsigned)u) << 16);
}
__device__ inline void split1(float x, unsigned short& hi, unsigned short& lo) {
    hi = f32_to_bf16(x);
    lo = f32_to_bf16(x - bf16_to_f32(hi));
}
// 1-transcendental tanh: exact limits at +/-inf, ~1e-6 abs err.
__device__ inline float fast_tanh(float x) {
    float ax = fabsf(x);
    float e  = __expf(2.f * ax);
    float t  = 1.f - 2.f / (e + 1.f);
    return copysignf(t, x);
}

// Packed-fragment index for a [384][128] bf16 matrix (B-operand layout):
// element (g,k): w=(g&127)>>4, gate=g>>7, l15=g&15, k0=k>>5, hi8=(k&31)>>3,
// j=k&7, lane=hi8*16+l15 ; short idx = (((w*3+gate)*4+k0)*64+lane)*8+j.
// One wave fragment = one contiguous 1KB burst; col-half ch occupies the
// contiguous slice [ch*24576, (ch+1)*24576) shorts.
__device__ inline size_t pack_idx(int g, int k) {
    int gate = g >> 7, c = g & 127;
    int w = c >> 4, l15 = c & 15;
    int k0 = k >> 5, r = k & 31, hi8 = r >> 3, j = r & 7;
    int lane = hi8 * 16 + l15;
    return ((size_t)(((w * 3 + gate) * 4 + k0) * 64 + lane)) * 8 + j;
}

// ---------------------------------------------------------------- W_c, bc ---
__global__ __launch_bounds__(128) void pack_wc_kernel(const float* __restrict__ W_ih,
                                                      const float* __restrict__ W,
                                                      unsigned short* __restrict__ Wcpk) {
    int g = blockIdx.x;          // 0..383
    int k = threadIdx.x;         // 0..127
    float acc = 0.f;
    for (int j = 0; j < 128; ++j)
        acc += W_ih[g * 128 + j] * W[j * 128 + k];
    Wcpk[pack_idx(g, k)] = f32_to_bf16(acc);
}

__global__ __launch_bounds__(256) void pack_whh_kernel(const float* __restrict__ W_hh,
                                                       unsigned short* __restrict__ Whpk) {
    int i = blockIdx.x * 256 + threadIdx.x;
    if (i >= 384 * 128) return;
    Whpk[pack_idx(i >> 7, i & 127)] = f32_to_bf16(W_hh[i]);
}

__global__ __launch_bounds__(384) void bc_kernel(const float* __restrict__ W_ih,
                                                 const float* __restrict__ b,
                                                 float* __restrict__ bc) {
    int g = threadIdx.x;
    if (g >= 384) return;
    float acc = 0.f;
    for (int j = 0; j < 128; ++j)
        acc += W_ih[g * 128 + j] * b[j];
    bc[g] = acc;
}

// ---------------------------------------------------------------- init h ----
__global__ __launch_bounds__(256) void init_h_kernel(const float* __restrict__ f,
                                                     unsigned short* __restrict__ h_hi,
                                                     unsigned short* __restrict__ h_lo) {
    int idx = blockIdx.x * 256 + threadIdx.x;          // over N*32 float4
    if (idx >= N_NODES * 32) return;
    int r = idx >> 5, c4 = idx & 31;
    float4 v = make_float4(0.f, 0.f, 0.f, 0.f);
    if (c4 < 16) v = ((const float4*)f)[r * 16 + c4];
    ushort4 hv, lv;
    split1(v.x, hv.x, lv.x); split1(v.y, hv.y, lv.y);
    split1(v.z, hv.z, lv.z); split1(v.w, hv.w, lv.w);
    ((ushort4*)h_hi)[idx] = hv;
    ((ushort4*)h_lo)[idx] = lv;
}

// ---------------------------------------------------------------- finalize --
__global__ __launch_bounds__(256) void finalize_kernel(const unsigned short* __restrict__ h_hi,
                                                       const unsigned short* __restrict__ h_lo,
                                                       float* __restrict__ out) {
    int idx = blockIdx.x * 256 + threadIdx.x;          // over N*32 quads
    if (idx >= N_NODES * 32) return;
    ushort4 hv = ((const ushort4*)h_hi)[idx];
    ushort4 lv = ((const ushort4*)h_lo)[idx];
    float4 o;
    o.x = bf16_to_f32(hv.x) + bf16_to_f32(lv.x);
    o.y = bf16_to_f32(hv.y) + bf16_to_f32(lv.y);
    o.z = bf16_to_f32(hv.z) + bf16_to_f32(lv.z);
    o.w = bf16_to_f32(hv.w) + bf16_to_f32(lv.w);
    ((float4*)out)[idx] = o;
}

// ---------------------------------------------------------------- CSR build -
__global__ __launch_bounds__(256) void fill_xcd_kernel(const int* __restrict__ src,
                                                       const int* __restrict__ dst,
                                                       int* __restrict__ cnt,
                                                       int* __restrict__ csr_src) {
    const int grp  = blockIdx.x & (NGRP - 1);
    const int bing = blockIdx.x / NGRP;          // block index within group
    const int nbg  = gridDim.x / NGRP;           // blocks per group
    const int lo   = grp * NODES_PER_GRP;
    const int hi   = lo + NODES_PER_GRP;
    for (int e = bing * 256 + threadIdx.x; e < N_EDGES; e += nbg * 256) {
        int d = __builtin_nontemporal_load(dst + e);
        if (d >= lo && d < hi) {
            int s = __builtin_nontemporal_load(src + e);
            int pos = atomicAdd(&cnt[d], 1);
            if (pos < CSTRIDE) csr_src[(size_t)d * CSTRIDE + pos] = s;
        }
    }
}

// ---------------------------------------------------------------- gather ----
// s_pair[n] = split( sum_{in-edges} h_hi[src] )   one wave per node.
// 16-deep load batches (indices via 4x int4, 16 row loads in flight):
// deg~16 -> typically ONE idx exposure + ONE row exposure. Register arrays
// are 16-deep (li[16]+u[16] ~ 50 VGPR total) — round-17 lesson: 48-deep
// arrays spilled to scratch (VGPR=56, FETCH 182MB) and cost 1.7x.
__global__ __launch_bounds__(256) void gather_kernel(const unsigned int* __restrict__ hhu,
                                                     const int* __restrict__ cnt,
                                                     const int* __restrict__ csr_src,
                                                     unsigned short* __restrict__ s_hi,
                                                     unsigned short* __restrict__ s_lo) {
    int node = blockIdx.x * 4 + (threadIdx.x >> 6);
    int lane = threadIdx.x & 63;
    int deg = cnt[node];
    int end = (deg < CSTRIDE) ? deg : CSTRIDE;
    const int* lst = csr_src + (size_t)node * CSTRIDE;
    float a0 = 0.f, a1 = 0.f;
    int i = 0;
    for (; i + 15 < end; i += 16) {
        int4 p0 = *(const int4*)&lst[i];
        int4 p1 = *(const int4*)&lst[i + 4];
        int4 p2 = *(const int4*)&lst[i + 8];
        int4 p3 = *(const int4*)&lst[i + 12];
        int li[16] = {p0.x, p0.y, p0.z, p0.w, p1.x, p1.y, p1.z, p1.w,
                      p2.x, p2.y, p2.z, p2.w, p3.x, p3.y, p3.z, p3.w};
        unsigned u[16];
#pragma unroll
        for (int j = 0; j < 16; ++j)
            u[j] = hhu[(size_t)li[j] * 64 + lane];
#pragma unroll
        for (int j = 0; j < 16; ++j) {
            a0 += __uint_as_float(u[j] << 16);
            a1 += __uint_as_float(u[j] & 0xffff0000u);
        }
    }
    if (i + 7 < end) {
        int4 p0 = *(const int4*)&lst[i];
        int4 p1 = *(const int4*)&lst[i + 4];
        int li[8] = {p0.x, p0.y, p0.z, p0.w, p1.x, p1.y, p1.z, p1.w};
        unsigned u[8];
#pragma unroll
        for (int j = 0; j < 8; ++j)
            u[j] = hhu[(size_t)li[j] * 64 + lane];
#pragma unroll
        for (int j = 0; j < 8; ++j) {
            a0 += __uint_as_float(u[j] << 16);
            a1 += __uint_as_float(u[j] & 0xffff0000u);
        }
        i += 8;
    }
    for (; i < end; ++i) {
        unsigned u0 = hhu[(size_t)lst[i] * 64 + lane];
        a0 += __uint_as_float(u0 << 16);
        a1 += __uint_as_float(u0 & 0xffff0000u);
    }
    unsigned short h0, l0, h1, l1;
    split1(a0, h0, l0);
    split1(a1, h1, l1);
    ((ushort2*)s_hi)[(size_t)node * 64 + lane] = (ushort2){h0, h1};
    ((ushort2*)s_lo)[(size_t)node * 64 + lane] = (ushort2){l0, l1};
}

// ---------------------------------------------------------------- GRU -------
// LDS-weight-stationary GRU + async reg-staged act pipeline (T14) with
// double-buffered, XOR-swizzled act LDS. h ping-pong -> h_in read-only, so
// the ONLY barrier is the per-tile LDS buffer flip (safe: a wave at most 1
// iteration ahead writes the OTHER buffer).
__global__ __launch_bounds__(512, 1) void gru_ps2_kernel(
        const unsigned short* __restrict__ s_hi,
        const unsigned short* __restrict__ s_lo,
        const unsigned short* __restrict__ hin_hi,
        const unsigned short* __restrict__ hin_lo,
        unsigned short* __restrict__ hout_hi,
        unsigned short* __restrict__ hout_lo,
        const unsigned short* __restrict__ Wcpk,
        const unsigned short* __restrict__ Whpk,
        const float* __restrict__ bc,
        const float* __restrict__ b_ih,
        const float* __restrict__ b_hh,
        const int* __restrict__ cnt) {
    __shared__ unsigned short lwc[24576];        // 48KB Wc col-half
    __shared__ unsigned short lwh[24576];        // 48KB Whh col-half
    __shared__ unsigned short abuf[2][3][4096];  // 2 x {s_hi,s_lo,h_hi} x 8KB

    const int tid  = threadIdx.x;
    const int lane = tid & 63;
    const int wv   = tid >> 6;              // 0..7
    const int w4   = wv & 3;                // col slice within half
    const int nt   = wv >> 2;               // node subtile 0/1
    const int l15  = lane & 15, hi8 = lane >> 4;
    const int ch   = blockIdx.x & 1;
    const int c    = ch * 64 + w4 * 16 + l15;

    // ---- stage this col-half's weights into LDS (once per block)
    {
        const ushort4* gC = (const ushort4*)(Wcpk + (size_t)ch * 24576);
        const ushort4* gH = (const ushort4*)(Whpk + (size_t)ch * 24576);
        ushort4* dC = (ushort4*)lwc;
        ushort4* dH = (ushort4*)lwh;
#pragma unroll
        for (int i = 0; i < 12; ++i) {
            dC[tid + 512 * i] = gC[tid + 512 * i];
            dH[tid + 512 * i] = gH[tid + 512 * i];
        }
    }
    __syncthreads();

    // ---- hoist weight fragments to registers (24 x b128, once)
    short8 wcr[3][4], whr[3][4];
#pragma unroll
    for (int g = 0; g < 3; ++g)
#pragma unroll
        for (int k0 = 0; k0 < 4; ++k0) {
            int fo = (((w4 * 3 + g) * 4 + k0) * 64 + lane) * 8;
            wcr[g][k0] = *(const short8*)&lwc[fo];
            whr[g][k0] = *(const short8*)&lwh[fo];
        }

    const float bcr = bc[c],   bcz = bc[128 + c],   bcn = bc[256 + c];
    const float bir = b_ih[c], biz = b_ih[128 + c], bin = b_ih[256 + c];
    const float bhr = b_hh[c], bhz = b_hh[128 + c], bhn = b_hh[256 + c];

    // ---- act staging geometry: thread owns 16B chunk o of the 8KB tile
    const int o  = tid * 16;                         // linear byte offset
    const int os = o ^ (((o >> 8) & 7) << 4);        // swizzled LDS offset
    const int arow = nt * 16 + l15;
    const int asw  = (arow & 7) << 4;

    const int tstep = gridDim.x >> 1;                // 256
    int tile = blockIdx.x >> 1;

    short8 rs, rl, rh;
    if (tile < GRU_NT) {
        size_t gb = (size_t)tile * 32 * 256 + o;     // byte offset into acts
        rs = *(const short8*)((const char*)s_hi  + gb);
        rl = *(const short8*)((const char*)s_lo  + gb);
        rh = *(const short8*)((const char*)hin_hi + gb);
    }
    int pb = 0;
    for (; tile < GRU_NT; tile += tstep) {
        // ---- commit staged regs to LDS buf pb, flip barrier
        *(short8*)((char*)abuf[pb][0] + os) = rs;
        *(short8*)((char*)abuf[pb][1] + os) = rl;
        *(short8*)((char*)abuf[pb][2] + os) = rh;
        __syncthreads();

        // ---- issue next tile's global loads (hide under MFMA below)
        int ntile = tile + tstep;
        if (ntile < GRU_NT) {
            size_t gb = (size_t)ntile * 32 * 256 + o;
            rs = *(const short8*)((const char*)s_hi  + gb);
            rl = *(const short8*)((const char*)s_lo  + gb);
            rh = *(const short8*)((const char*)hin_hi + gb);
        }

        // ---- hold + deg (own coords; issued before MFMA to overlap)
        const int n0 = tile * 32 + nt * 16;
        float hold[4], dg[4];
#pragma unroll
        for (int r = 0; r < 4; ++r) {
            int row = n0 + hi8 * 4 + r;
            size_t gidx = (size_t)row * 128 + c;
            hold[r] = bf16_to_f32(hin_hi[gidx]) + bf16_to_f32(hin_lo[gidx]);
            dg[r]   = (float)cnt[row];
        }

        // ---- MFMAs from act LDS + register weights
        f32x4 z1[3], z2[3];
#pragma unroll
        for (int g = 0; g < 3; ++g) {
            z1[g] = (f32x4){0.f, 0.f, 0.f, 0.f};
            z2[g] = (f32x4){0.f, 0.f, 0.f, 0.f};
        }
#pragma unroll
        for (int k0 = 0; k0 < 4; ++k0) {
            int pa = arow * 256 + k0 * 64 + hi8 * 16;   // logical byte offset
            int ps = pa ^ asw;
            short8 ash = *(const short8*)((const char*)abuf[pb][0] + ps);
            short8 asl = *(const short8*)((const char*)abuf[pb][1] + ps);
            short8 ahh = *(const short8*)((const char*)abuf[pb][2] + ps);
#pragma unroll
            for (int g = 0; g < 3; ++g) {
                z1[g] = __builtin_amdgcn_mfma_f32_16x16x32_bf16(ash, wcr[g][k0], z1[g], 0, 0, 0);
                z1[g] = __builtin_amdgcn_mfma_f32_16x16x32_bf16(asl, wcr[g][k0], z1[g], 0, 0, 0);
                z2[g] = __builtin_amdgcn_mfma_f32_16x16x32_bf16(ahh, whr[g][k0], z2[g], 0, 0, 0);
            }
        }

        // ---- gates + h_out pair (disjoint from h_in: no extra barrier)
#pragma unroll
        for (int r = 0; r < 4; ++r) {
            int row = n0 + hi8 * 4 + r;
            size_t gidx = (size_t)row * 128 + c;
            float d = dg[r];
            float rr = 1.f / (1.f + __expf(-(z1[0][r] + d * bcr + bir + z2[0][r] + bhr)));
            float zz = 1.f / (1.f + __expf(-(z1[1][r] + d * bcz + biz + z2[1][r] + bhz)));
            float nn_ = fast_tanh(z1[2][r] + d * bcn + bin + rr * (z2[2][r] + bhn));
            float hn = (1.f - zz) * nn_ + zz * hold[r];
            unsigned short shh, sll;
            split1(hn, shh, sll);
            hout_hi[gidx] = shh;
            hout_lo[gidx] = sll;
        }
        pb ^= 1;
    }
}

// ---------------------------------------------------------------- launch ----
extern "C" void kernel_launch(void* const* d_in, const int* in_sizes, int n_in,
                              void* d_out, int out_size, void* d_ws, size_t ws_size,
                              hipStream_t stream) {
    const float* feat = (const float*)d_in[0];
    const float* W    = (const float*)d_in[1];
    const float* b    = (const float*)d_in[2];
    const float* W_ih = (const float*)d_in[3];
    const float* W_hh = (const float*)d_in[4];
    const float* b_ih = (const float*)d_in[5];
    const float* b_hh = (const float*)d_in[6];
    const int*   src  = (const int*)d_in[7];
    const int*   dst  = (const int*)d_in[8];

    // s-pair parks in d_out during the steps (exact fit: N*128*4 bytes);
    // finalize_kernel rewrites d_out with f32 h at the end.
    unsigned short* s_hi = (unsigned short*)d_out;
    unsigned short* s_lo = s_hi + (size_t)N_NODES * 128;

    char* w = (char*)d_ws;
    unsigned short* hA_hi = (unsigned short*)w; w += (size_t)N_NODES * 128 * 2;
    unsigned short* hA_lo = (unsigned short*)w; w += (size_t)N_NODES * 128 * 2;
    unsigned short* hB_hi = (unsigned short*)w; w += (size_t)N_NODES * 128 * 2;
    unsigned short* hB_lo = (unsigned short*)w; w += (size_t)N_NODES * 128 * 2;
    unsigned short* Wcpk  = (unsigned short*)w; w += (size_t)384 * 128 * 2;
    unsigned short* Whpk  = (unsigned short*)w; w += (size_t)384 * 128 * 2;
    float*          bc    = (float*)w;          w += 384 * 4;
    int*            cnt   = (int*)w;            w += (size_t)N_NODES * 4;
    int*            csr_src = (int*)w;          w += (size_t)N_NODES * CSTRIDE * 4;  // 19.2 MB

    const int elem_blocks = (N_NODES * 32 + 255) / 256;
    const int gath_blocks = N_NODES / 4;                  // 25000 (exact)

    init_h_kernel<<<elem_blocks, 256, 0, stream>>>(feat, hA_hi, hA_lo);
    pack_wc_kernel<<<384, 128, 0, stream>>>(W_ih, W, Wcpk);
    pack_whh_kernel<<<(384 * 128 + 255) / 256, 256, 0, stream>>>(W_hh, Whpk);
    bc_kernel<<<1, 384, 0, stream>>>(W_ih, b, bc);

    // ---- XCD-partitioned bucket CSR (one pass; cnt = exact degrees)
    hipMemsetAsync(cnt, 0, (size_t)N_NODES * 4, stream);
    fill_xcd_kernel<<<1024, 256, 0, stream>>>(src, dst, cnt, csr_src);

    // ---- 3 steps with h ping-pong: A->B, B->A, A->B
    unsigned short* hi_in[3]  = {hA_hi, hB_hi, hA_hi};
    unsigned short* lo_in[3]  = {hA_lo, hB_lo, hA_lo};
    unsigned short* hi_out[3] = {hB_hi, hA_hi, hB_hi};
    unsigned short* lo_out[3] = {hB_lo, hA_lo, hB_lo};
    for (int s = 0; s < 3; ++s) {
        gather_kernel<<<gath_blocks, 256, 0, stream>>>((const unsigned int*)hi_in[s],
                                                       cnt, csr_src, s_hi, s_lo);
        gru_ps2_kernel<<<512, 512, 0, stream>>>(s_hi, s_lo,
                                                hi_in[s], lo_in[s],
                                                hi_out[s], lo_out[s],
                                                Wcpk, Whpk, bc, b_ih, b_hh, cnt);
    }
    finalize_kernel<<<elem_blocks, 256, 0, stream>>>(hB_hi, hB_lo, (float*)d_out);
}

// Round 19
// 519.281 us; speedup vs baseline: 1.3599x; 1.0524x over previous
//
#include <hip/hip_runtime.h>
#include <math.h>

#define N_NODES 100000
#define N_EDGES 1600000
#define CSTRIDE 48   // fixed CSR stride (ints): max degree for E/N=16 Poisson ~36, P(>48)~1e-9/node
#define NGRP 8       // XCD groups for the CSR build
#define NODES_PER_GRP ((N_NODES + NGRP - 1) / NGRP)   // 12500
#define GRU_NT (N_NODES / 32)                          // 3125 tiles

typedef __attribute__((ext_vector_type(8))) short short8;
typedef __attribute__((ext_vector_type(4))) float f32x4;

__device__ inline unsigned short f32_to_bf16(float x) {
    unsigned u = __float_as_uint(x);
    unsigned r = u + 0x7fff + ((u >> 16) & 1);   // RNE
    return (unsigned short)(r >> 16);
}
__device__ inline float bf16_to_f32(unsigned short u) {
    return __uint_as_float(((unsigned)u) << 16);
}
__device__ inline void split1(float x, unsigned short& hi, unsigned short& lo) {
    hi = f32_to_bf16(x);
    lo = f32_to_bf16(x - bf16_to_f32(hi));
}
// 1-transcendental tanh: exact limits at +/-inf, ~1e-6 abs err.
__device__ inline float fast_tanh(float x) {
    float ax = fabsf(x);
    float e  = __expf(2.f * ax);
    float t  = 1.f - 2.f / (e + 1.f);
    return copysignf(t, x);
}

// Packed-fragment index for a [384][128] bf16 matrix (B-operand layout):
// element (g,k): w=(g&127)>>4, gate=g>>7, l15=g&15, k0=k>>5, hi8=(k&31)>>3,
// j=k&7, lane=hi8*16+l15 ; short idx = (((w*3+gate)*4+k0)*64+lane)*8+j.
// One wave fragment = one contiguous 1KB burst; col-half ch occupies the
// contiguous slice [ch*24576, (ch+1)*24576) shorts.
__device__ inline size_t pack_idx(int g, int k) {
    int gate = g >> 7, c = g & 127;
    int w = c >> 4, l15 = c & 15;
    int k0 = k >> 5, r = k & 31, hi8 = r >> 3, j = r & 7;
    int lane = hi8 * 16 + l15;
    return ((size_t)(((w * 3 + gate) * 4 + k0) * 64 + lane)) * 8 + j;
}

// ---------------------------------------------------------------- W_c, bc ---
__global__ __launch_bounds__(128) void pack_wc_kernel(const float* __restrict__ W_ih,
                                                      const float* __restrict__ W,
                                                      unsigned short* __restrict__ Wcpk) {
    int g = blockIdx.x;          // 0..383
    int k = threadIdx.x;         // 0..127
    float acc = 0.f;
    for (int j = 0; j < 128; ++j)
        acc += W_ih[g * 128 + j] * W[j * 128 + k];
    Wcpk[pack_idx(g, k)] = f32_to_bf16(acc);
}

__global__ __launch_bounds__(256) void pack_whh_kernel(const float* __restrict__ W_hh,
                                                       unsigned short* __restrict__ Whpk) {
    int i = blockIdx.x * 256 + threadIdx.x;
    if (i >= 384 * 128) return;
    Whpk[pack_idx(i >> 7, i & 127)] = f32_to_bf16(W_hh[i]);
}

__global__ __launch_bounds__(384) void bc_kernel(const float* __restrict__ W_ih,
                                                 const float* __restrict__ b,
                                                 float* __restrict__ bc) {
    int g = threadIdx.x;
    if (g >= 384) return;
    float acc = 0.f;
    for (int j = 0; j < 128; ++j)
        acc += W_ih[g * 128 + j] * b[j];
    bc[g] = acc;
}

// ---------------------------------------------------------------- init h ----
__global__ __launch_bounds__(256) void init_h_kernel(const float* __restrict__ f,
                                                     unsigned short* __restrict__ h_hi,
                                                     unsigned short* __restrict__ h_lo) {
    int idx = blockIdx.x * 256 + threadIdx.x;          // over N*32 float4
    if (idx >= N_NODES * 32) return;
    int r = idx >> 5, c4 = idx & 31;
    float4 v = make_float4(0.f, 0.f, 0.f, 0.f);
    if (c4 < 16) v = ((const float4*)f)[r * 16 + c4];
    ushort4 hv, lv;
    split1(v.x, hv.x, lv.x); split1(v.y, hv.y, lv.y);
    split1(v.z, hv.z, lv.z); split1(v.w, hv.w, lv.w);
    ((ushort4*)h_hi)[idx] = hv;
    ((ushort4*)h_lo)[idx] = lv;
}

// ---------------------------------------------------------------- finalize --
__global__ __launch_bounds__(256) void finalize_kernel(const unsigned short* __restrict__ h_hi,
                                                       const unsigned short* __restrict__ h_lo,
                                                       float* __restrict__ out) {
    int idx = blockIdx.x * 256 + threadIdx.x;          // over N*32 quads
    if (idx >= N_NODES * 32) return;
    ushort4 hv = ((const ushort4*)h_hi)[idx];
    ushort4 lv = ((const ushort4*)h_lo)[idx];
    float4 o;
    o.x = bf16_to_f32(hv.x) + bf16_to_f32(lv.x);
    o.y = bf16_to_f32(hv.y) + bf16_to_f32(lv.y);
    o.z = bf16_to_f32(hv.z) + bf16_to_f32(lv.z);
    o.w = bf16_to_f32(hv.w) + bf16_to_f32(lv.w);
    ((float4*)out)[idx] = o;
}

// ---------------------------------------------------------------- CSR build -
// XCD-partitioned bucket fill, 4-edge vector streaming.
// Round-18 post-mortem: VALUBusy 3.8%, HBM 14% -> latency-bound on the
// serialized 1-edge-per-iter nt load chain. Now each iter streams 4 dst +
// 4 src via int4 (no conditional load, no dependent chain); grid 2048 ->
// 32 waves/CU. nt keeps the csr slice resident in the XCD's L2.
__global__ __launch_bounds__(256) void fill_xcd_kernel(const int* __restrict__ src,
                                                       const int* __restrict__ dst,
                                                       int* __restrict__ cnt,
                                                       int* __restrict__ csr_src) {
    const int grp  = blockIdx.x & (NGRP - 1);
    const int bing = blockIdx.x / NGRP;          // block index within group
    const int nbg  = gridDim.x / NGRP;           // blocks per group
    const int lo   = grp * NODES_PER_GRP;
    const int hi   = lo + NODES_PER_GRP;
    const int step = nbg * 256 * 4;
    for (int e = (bing * 256 + threadIdx.x) * 4; e < N_EDGES; e += step) {
        int4 d4, s4;
        d4.x = __builtin_nontemporal_load(dst + e);
        d4.y = __builtin_nontemporal_load(dst + e + 1);
        d4.z = __builtin_nontemporal_load(dst + e + 2);
        d4.w = __builtin_nontemporal_load(dst + e + 3);
        s4.x = __builtin_nontemporal_load(src + e);
        s4.y = __builtin_nontemporal_load(src + e + 1);
        s4.z = __builtin_nontemporal_load(src + e + 2);
        s4.w = __builtin_nontemporal_load(src + e + 3);
#pragma unroll
        for (int j = 0; j < 4; ++j) {
            int d = (j == 0) ? d4.x : (j == 1) ? d4.y : (j == 2) ? d4.z : d4.w;
            int s = (j == 0) ? s4.x : (j == 1) ? s4.y : (j == 2) ? s4.z : s4.w;
            if (d >= lo && d < hi) {
                int pos = atomicAdd(&cnt[d], 1);
                if (pos < CSTRIDE) csr_src[(size_t)d * CSTRIDE + pos] = s;
            }
        }
    }
}

// ---------------------------------------------------------------- gather ----
// s_pair[n] = split( sum_{in-edges} h_hi[src] )   one wave per node.
// 16-deep load batches (indices via 4x int4, 16 row loads in flight):
// deg~16 -> typically ONE idx exposure + ONE row exposure. Register arrays
// are 16-deep (li[16]+u[16] ~ 50 VGPR total) — round-17 lesson: 48-deep
// arrays spilled to scratch (VGPR=56, FETCH 182MB) and cost 1.7x.
__global__ __launch_bounds__(256) void gather_kernel(const unsigned int* __restrict__ hhu,
                                                     const int* __restrict__ cnt,
                                                     const int* __restrict__ csr_src,
                                                     unsigned short* __restrict__ s_hi,
                                                     unsigned short* __restrict__ s_lo) {
    int node = blockIdx.x * 4 + (threadIdx.x >> 6);
    int lane = threadIdx.x & 63;
    int deg = cnt[node];
    int end = (deg < CSTRIDE) ? deg : CSTRIDE;
    const int* lst = csr_src + (size_t)node * CSTRIDE;
    float a0 = 0.f, a1 = 0.f;
    int i = 0;
    for (; i + 15 < end; i += 16) {
        int4 p0 = *(const int4*)&lst[i];
        int4 p1 = *(const int4*)&lst[i + 4];
        int4 p2 = *(const int4*)&lst[i + 8];
        int4 p3 = *(const int4*)&lst[i + 12];
        int li[16] = {p0.x, p0.y, p0.z, p0.w, p1.x, p1.y, p1.z, p1.w,
                      p2.x, p2.y, p2.z, p2.w, p3.x, p3.y, p3.z, p3.w};
        unsigned u[16];
#pragma unroll
        for (int j = 0; j < 16; ++j)
            u[j] = hhu[(size_t)li[j] * 64 + lane];
#pragma unroll
        for (int j = 0; j < 16; ++j) {
            a0 += __uint_as_float(u[j] << 16);
            a1 += __uint_as_float(u[j] & 0xffff0000u);
        }
    }
    if (i + 7 < end) {
        int4 p0 = *(const int4*)&lst[i];
        int4 p1 = *(const int4*)&lst[i + 4];
        int li[8] = {p0.x, p0.y, p0.z, p0.w, p1.x, p1.y, p1.z, p1.w};
        unsigned u[8];
#pragma unroll
        for (int j = 0; j < 8; ++j)
            u[j] = hhu[(size_t)li[j] * 64 + lane];
#pragma unroll
        for (int j = 0; j < 8; ++j) {
            a0 += __uint_as_float(u[j] << 16);
            a1 += __uint_as_float(u[j] & 0xffff0000u);
        }
        i += 8;
    }
    for (; i < end; ++i) {
        unsigned u0 = hhu[(size_t)lst[i] * 64 + lane];
        a0 += __uint_as_float(u0 << 16);
        a1 += __uint_as_float(u0 & 0xffff0000u);
    }
    unsigned short h0, l0, h1, l1;
    split1(a0, h0, l0);
    split1(a1, h1, l1);
    ((ushort2*)s_hi)[(size_t)node * 64 + lane] = (ushort2){h0, h1};
    ((ushort2*)s_lo)[(size_t)node * 64 + lane] = (ushort2){l0, l1};
}

// ---------------------------------------------------------------- GRU -------
// LDS-weight-stationary GRU + async reg-staged act pipeline (T14) with
// double-buffered, XOR-swizzled act LDS. h ping-pong -> h_in read-only, so
// the ONLY barrier is the per-tile LDS buffer flip (safe: a wave at most 1
// iteration ahead writes the OTHER buffer).
__global__ __launch_bounds__(512, 1) void gru_ps2_kernel(
        const unsigned short* __restrict__ s_hi,
        const unsigned short* __restrict__ s_lo,
        const unsigned short* __restrict__ hin_hi,
        const unsigned short* __restrict__ hin_lo,
        unsigned short* __restrict__ hout_hi,
        unsigned short* __restrict__ hout_lo,
        const unsigned short* __restrict__ Wcpk,
        const unsigned short* __restrict__ Whpk,
        const float* __restrict__ bc,
        const float* __restrict__ b_ih,
        const float* __restrict__ b_hh,
        const int* __restrict__ cnt) {
    __shared__ unsigned short lwc[24576];        // 48KB Wc col-half
    __shared__ unsigned short lwh[24576];        // 48KB Whh col-half
    __shared__ unsigned short abuf[2][3][4096];  // 2 x {s_hi,s_lo,h_hi} x 8KB

    const int tid  = threadIdx.x;
    const int lane = tid & 63;
    const int wv   = tid >> 6;              // 0..7
    const int w4   = wv & 3;                // col slice within half
    const int nt   = wv >> 2;               // node subtile 0/1
    const int l15  = lane & 15, hi8 = lane >> 4;
    const int ch   = blockIdx.x & 1;
    const int c    = ch * 64 + w4 * 16 + l15;

    // ---- stage this col-half's weights into LDS (once per block)
    {
        const ushort4* gC = (const ushort4*)(Wcpk + (size_t)ch * 24576);
        const ushort4* gH = (const ushort4*)(Whpk + (size_t)ch * 24576);
        ushort4* dC = (ushort4*)lwc;
        ushort4* dH = (ushort4*)lwh;
#pragma unroll
        for (int i = 0; i < 12; ++i) {
            dC[tid + 512 * i] = gC[tid + 512 * i];
            dH[tid + 512 * i] = gH[tid + 512 * i];
        }
    }
    __syncthreads();

    // ---- hoist weight fragments to registers (24 x b128, once)
    short8 wcr[3][4], whr[3][4];
#pragma unroll
    for (int g = 0; g < 3; ++g)
#pragma unroll
        for (int k0 = 0; k0 < 4; ++k0) {
            int fo = (((w4 * 3 + g) * 4 + k0) * 64 + lane) * 8;
            wcr[g][k0] = *(const short8*)&lwc[fo];
            whr[g][k0] = *(const short8*)&lwh[fo];
        }

    const float bcr = bc[c],   bcz = bc[128 + c],   bcn = bc[256 + c];
    const float bir = b_ih[c], biz = b_ih[128 + c], bin = b_ih[256 + c];
    const float bhr = b_hh[c], bhz = b_hh[128 + c], bhn = b_hh[256 + c];

    // ---- act staging geometry: thread owns 16B chunk o of the 8KB tile
    const int o  = tid * 16;                         // linear byte offset
    const int os = o ^ (((o >> 8) & 7) << 4);        // swizzled LDS offset
    const int arow = nt * 16 + l15;
    const int asw  = (arow & 7) << 4;

    const int tstep = gridDim.x >> 1;                // 256
    int tile = blockIdx.x >> 1;

    short8 rs, rl, rh;
    if (tile < GRU_NT) {
        size_t gb = (size_t)tile * 32 * 256 + o;     // byte offset into acts
        rs = *(const short8*)((const char*)s_hi  + gb);
        rl = *(const short8*)((const char*)s_lo  + gb);
        rh = *(const short8*)((const char*)hin_hi + gb);
    }
    int pb = 0;
    for (; tile < GRU_NT; tile += tstep) {
        // ---- commit staged regs to LDS buf pb, flip barrier
        *(short8*)((char*)abuf[pb][0] + os) = rs;
        *(short8*)((char*)abuf[pb][1] + os) = rl;
        *(short8*)((char*)abuf[pb][2] + os) = rh;
        __syncthreads();

        // ---- issue next tile's global loads (hide under MFMA below)
        int ntile = tile + tstep;
        if (ntile < GRU_NT) {
            size_t gb = (size_t)ntile * 32 * 256 + o;
            rs = *(const short8*)((const char*)s_hi  + gb);
            rl = *(const short8*)((const char*)s_lo  + gb);
            rh = *(const short8*)((const char*)hin_hi + gb);
        }

        // ---- hold + deg (own coords; issued before MFMA to overlap)
        const int n0 = tile * 32 + nt * 16;
        float hold[4], dg[4];
#pragma unroll
        for (int r = 0; r < 4; ++r) {
            int row = n0 + hi8 * 4 + r;
            size_t gidx = (size_t)row * 128 + c;
            hold[r] = bf16_to_f32(hin_hi[gidx]) + bf16_to_f32(hin_lo[gidx]);
            dg[r]   = (float)cnt[row];
        }

        // ---- MFMAs from act LDS + register weights
        f32x4 z1[3], z2[3];
#pragma unroll
        for (int g = 0; g < 3; ++g) {
            z1[g] = (f32x4){0.f, 0.f, 0.f, 0.f};
            z2[g] = (f32x4){0.f, 0.f, 0.f, 0.f};
        }
#pragma unroll
        for (int k0 = 0; k0 < 4; ++k0) {
            int pa = arow * 256 + k0 * 64 + hi8 * 16;   // logical byte offset
            int ps = pa ^ asw;
            short8 ash = *(const short8*)((const char*)abuf[pb][0] + ps);
            short8 asl = *(const short8*)((const char*)abuf[pb][1] + ps);
            short8 ahh = *(const short8*)((const char*)abuf[pb][2] + ps);
#pragma unroll
            for (int g = 0; g < 3; ++g) {
                z1[g] = __builtin_amdgcn_mfma_f32_16x16x32_bf16(ash, wcr[g][k0], z1[g], 0, 0, 0);
                z1[g] = __builtin_amdgcn_mfma_f32_16x16x32_bf16(asl, wcr[g][k0], z1[g], 0, 0, 0);
                z2[g] = __builtin_amdgcn_mfma_f32_16x16x32_bf16(ahh, whr[g][k0], z2[g], 0, 0, 0);
            }
        }

        // ---- gates + h_out pair (disjoint from h_in: no extra barrier)
#pragma unroll
        for (int r = 0; r < 4; ++r) {
            int row = n0 + hi8 * 4 + r;
            size_t gidx = (size_t)row * 128 + c;
            float d = dg[r];
            float rr = 1.f / (1.f + __expf(-(z1[0][r] + d * bcr + bir + z2[0][r] + bhr)));
            float zz = 1.f / (1.f + __expf(-(z1[1][r] + d * bcz + biz + z2[1][r] + bhz)));
            float nn_ = fast_tanh(z1[2][r] + d * bcn + bin + rr * (z2[2][r] + bhn));
            float hn = (1.f - zz) * nn_ + zz * hold[r];
            unsigned short shh, sll;
            split1(hn, shh, sll);
            hout_hi[gidx] = shh;
            hout_lo[gidx] = sll;
        }
        pb ^= 1;
    }
}

// ---------------------------------------------------------------- launch ----
extern "C" void kernel_launch(void* const* d_in, const int* in_sizes, int n_in,
                              void* d_out, int out_size, void* d_ws, size_t ws_size,
                              hipStream_t stream) {
    const float* feat = (const float*)d_in[0];
    const float* W    = (const float*)d_in[1];
    const float* b    = (const float*)d_in[2];
    const float* W_ih = (const float*)d_in[3];
    const float* W_hh = (const float*)d_in[4];
    const float* b_ih = (const float*)d_in[5];
    const float* b_hh = (const float*)d_in[6];
    const int*   src  = (const int*)d_in[7];
    const int*   dst  = (const int*)d_in[8];

    // s-pair parks in d_out during the steps (exact fit: N*128*4 bytes);
    // finalize_kernel rewrites d_out with f32 h at the end.
    unsigned short* s_hi = (unsigned short*)d_out;
    unsigned short* s_lo = s_hi + (size_t)N_NODES * 128;

    char* w = (char*)d_ws;
    unsigned short* hA_hi = (unsigned short*)w; w += (size_t)N_NODES * 128 * 2;
    unsigned short* hA_lo = (unsigned short*)w; w += (size_t)N_NODES * 128 * 2;
    unsigned short* hB_hi = (unsigned short*)w; w += (size_t)N_NODES * 128 * 2;
    unsigned short* hB_lo = (unsigned short*)w; w += (size_t)N_NODES * 128 * 2;
    unsigned short* Wcpk  = (unsigned short*)w; w += (size_t)384 * 128 * 2;
    unsigned short* Whpk  = (unsigned short*)w; w += (size_t)384 * 128 * 2;
    float*          bc    = (float*)w;          w += 384 * 4;
    int*            cnt   = (int*)w;            w += (size_t)N_NODES * 4;
    int*            csr_src = (int*)w;          w += (size_t)N_NODES * CSTRIDE * 4;  // 19.2 MB

    const int elem_blocks = (N_NODES * 32 + 255) / 256;
    const int gath_blocks = N_NODES / 4;                  // 25000 (exact)

    init_h_kernel<<<elem_blocks, 256, 0, stream>>>(feat, hA_hi, hA_lo);
    pack_wc_kernel<<<384, 128, 0, stream>>>(W_ih, W, Wcpk);
    pack_whh_kernel<<<(384 * 128 + 255) / 256, 256, 0, stream>>>(W_hh, Whpk);
    bc_kernel<<<1, 384, 0, stream>>>(W_ih, b, bc);

    // ---- XCD-partitioned bucket CSR (one pass; cnt = exact degrees)
    hipMemsetAsync(cnt, 0, (size_t)N_NODES * 4, stream);
    fill_xcd_kernel<<<2048, 256, 0, stream>>>(src, dst, cnt, csr_src);

    // ---- 3 steps with h ping-pong: A->B, B->A, A->B
    unsigned short* hi_in[3]  = {hA_hi, hB_hi, hA_hi};
    unsigned short* lo_in[3]  = {hA_lo, hB_lo, hA_lo};
    unsigned short* hi_out[3] = {hB_hi, hA_hi, hB_hi};
    unsigned short* lo_out[3] = {hB_lo, hA_lo, hB_lo};
    for (int s = 0; s < 3; ++s) {
        gather_kernel<<<gath_blocks, 256, 0, stream>>>((const unsigned int*)hi_in[s],
                                                       cnt, csr_src, s_hi, s_lo);
        gru_ps2_kernel<<<512, 512, 0, stream>>>(s_hi, s_lo,
                                                hi_in[s], lo_in[s],
                                                hi_out[s], lo_out[s],
                                                Wcpk, Whpk, bc, b_ih, b_hh, cnt);
    }
    finalize_kernel<<<elem_blocks, 256, 0, stream>>>(hB_hi, hB_lo, (float*)d_out);
}